// Round 1
// 151.220 us; speedup vs baseline: 1.0790x; 1.0790x over previous
//
#include <hip/hip_runtime.h>
#include <hip/hip_bf16.h>

#define N_PTS  4096
#define M_Q    16384
#define C_IN   256
#define C_SKIP 128
#define C_H    384      // C_IN + C_SKIP
#define HDIM   256
#define NSPLIT 16
#define PTS_PER_SPLIT (N_PTS / NSPLIT)   // 256

typedef __bf16 bf16x8 __attribute__((ext_vector_type(8)));
typedef float  f32x4  __attribute__((ext_vector_type(4)));

__device__ __forceinline__ void insert3(float d, int j,
                                        float& b0, float& b1, float& b2,
                                        int& i0, int& i1, int& i2) {
    if (d < b2) {
        if (d < b1) {
            b2 = b1; i2 = i1;
            if (d < b0) { b1 = b0; i1 = i0; b0 = d; i0 = j; }
            else        { b1 = d;  i1 = j; }
        } else { b2 = d; i2 = j; }
    }
}

// ---- Phase 0: fused prep — W1/W2 convert+transpose, pos4 build, out tail ---
__global__ __launch_bounds__(256) void prep_tail_kernel(
        const float* __restrict__ W1, const float* __restrict__ W2,
        const float* __restrict__ pos, const float* __restrict__ pos_skip,
        __hip_bfloat16* __restrict__ W1t, __hip_bfloat16* __restrict__ W2t,
        float4* __restrict__ pos4, float* __restrict__ out, int out_size) {
    const int i = blockIdx.x * 256 + threadIdx.x;
    if (i < C_H * HDIM) {
        const int k = i / HDIM, n = i % HDIM;
        W1t[n * C_H + k] = __float2bfloat16(W1[i]);
    } else if (i < C_H * HDIM + HDIM * HDIM) {
        const int j = i - C_H * HDIM;
        const int k = j / HDIM, n = j % HDIM;
        W2t[n * HDIM + k] = __float2bfloat16(W2[j]);
    } else if (i < C_H * HDIM + HDIM * HDIM + N_PTS) {
        const int j = i - (C_H * HDIM + HDIM * HDIM);
        const float px = pos[j*3+0], py = pos[j*3+1], pz = pos[j*3+2];
        pos4[j] = make_float4(px, py, pz, px*px + py*py + pz*pz);
    }
    // output tail: pos_skip passthrough + zero pad (runs before fused_mlp writes)
    if (i < M_Q * 3) out[(size_t)M_Q * HDIM + i] = pos_skip[i];
    const int zbase = M_Q * HDIM + M_Q * 3;
    if (zbase + i < out_size) out[zbase + i] = 0.0f;
}

// ---- Phase 1: partial kNN, 16-way split ------------------------------------
// Point stream via wave-uniform global reads (scalar s_load path) — NO LDS.
// Surrogate key d' = |p|^2 - 2 q.p (monotone-equivalent per query).
__global__ __launch_bounds__(256) void knn_part_kernel(
        const float4* __restrict__ pos4, const float* __restrict__ pos_skip,
        float* __restrict__ cand_d, int* __restrict__ cand_i) {
    const int s  = blockIdx.y;
    const int q  = blockIdx.x * 256 + threadIdx.x;
    const int j0 = s * PTS_PER_SPLIT;
    const float m2x = -2.0f * pos_skip[q*3+0];
    const float m2y = -2.0f * pos_skip[q*3+1];
    const float m2z = -2.0f * pos_skip[q*3+2];
    float b0 = 3e38f, b1 = 3e38f, b2 = 3e38f;
    int   i0 = 0, i1 = 0, i2 = 0;
    #pragma unroll 8
    for (int j = 0; j < PTS_PER_SPLIT; ++j) {
        const float4 p = pos4[j0 + j];      // uniform address -> SGPR broadcast
        const float d = fmaf(p.x, m2x, fmaf(p.y, m2y, fmaf(p.z, m2z, p.w)));
        const int  jj = j0 + j;
        const bool c2 = d < b2, c1 = d < b1, c0 = d < b0;
        b2 = c2 ? (c1 ? b1 : d) : b2;  i2 = c2 ? (c1 ? i1 : jj) : i2;
        b1 = c1 ? (c0 ? b0 : d) : b1;  i1 = c1 ? (c0 ? i0 : jj) : i1;
        b0 = c0 ? d : b0;              i0 = c0 ? jj : i0;
    }
    // SoA rank-major layout: cand_d[r][s][q] -> 6 fully-coalesced dword stores
    const int base = s * M_Q + q;
    cand_d[0*NSPLIT*M_Q + base] = b0;
    cand_d[1*NSPLIT*M_Q + base] = b1;
    cand_d[2*NSPLIT*M_Q + base] = b2;
    cand_i[0*NSPLIT*M_Q + base] = i0;
    cand_i[1*NSPLIT*M_Q + base] = i1;
    cand_i[2*NSPLIT*M_Q + base] = i2;
}

// ---- Phase 2: merge 48 candidates (4 lanes/query) -> top-3 + weights -------
__global__ __launch_bounds__(256) void knn_merge_kernel(
        const float* __restrict__ cand_d, const int* __restrict__ cand_i,
        const float* __restrict__ pos, const float* __restrict__ pos_skip,
        int* __restrict__ idx, float* __restrict__ wn) {
    const int tid = blockIdx.x * 256 + threadIdx.x;
    const int q = tid >> 2;
    const int l = tid & 3;             // 4 lanes per query, lane l owns 4 splits
    float b0 = 3e38f, b1 = 3e38f, b2 = 3e38f;
    int   i0 = 0, i1 = 0, i2 = 0;
    const int SM = NSPLIT * M_Q;
    #pragma unroll
    for (int u = 0; u < NSPLIT/4; ++u) {
        const int s = l * (NSPLIT/4) + u;   // ascending split = ascending index, tie-break safe
        const int base = s * M_Q + q;
        const float d0 = cand_d[0*SM + base], d1 = cand_d[1*SM + base], d2c = cand_d[2*SM + base];
        const int   j0 = cand_i[0*SM + base], j1 = cand_i[1*SM + base], j2c = cand_i[2*SM + base];
        insert3(d0, j0,  b0,b1,b2, i0,i1,i2);
        insert3(d1, j1,  b0,b1,b2, i0,i1,i2);
        insert3(d2c, j2c, b0,b1,b2, i0,i1,i2);
    }
    // cross-lane merge; lower lane's triple is the base so ties keep lowest index
    #pragma unroll
    for (int m = 1; m <= 2; m <<= 1) {
        const float nb0 = __shfl_xor(b0, m), nb1 = __shfl_xor(b1, m), nb2 = __shfl_xor(b2, m);
        const int   ni0 = __shfl_xor(i0, m), ni1 = __shfl_xor(i1, m), ni2 = __shfl_xor(i2, m);
        const bool upper = (l & m) != 0;
        float e0 = upper ? b0 : nb0, e1 = upper ? b1 : nb1, e2 = upper ? b2 : nb2;
        int   f0 = upper ? i0 : ni0, f1 = upper ? i1 : ni1, f2 = upper ? i2 : ni2;
        if (upper) { b0 = nb0; b1 = nb1; b2 = nb2; i0 = ni0; i1 = ni1; i2 = ni2; }
        insert3(e0, f0, b0,b1,b2, i0,i1,i2);
        insert3(e1, f1, b0,b1,b2, i0,i1,i2);
        insert3(e2, f2, b0,b1,b2, i0,i1,i2);
    }
    if (l == 0) {
        const float qx = pos_skip[q*3+0], qy = pos_skip[q*3+1], qz = pos_skip[q*3+2];
        float w[3]; int ii[3] = {i0, i1, i2};
        #pragma unroll
        for (int r = 0; r < 3; ++r) {
            const float dx = qx - pos[ii[r]*3+0];
            const float dy = qy - pos[ii[r]*3+1];
            const float dz = qz - pos[ii[r]*3+2];
            const float d2 = dx*dx + dy*dy + dz*dz;   // exact recompute, like reference d2k
            w[r] = 1.0f / fmaxf(d2, 1e-16f);
        }
        const float inv = 1.0f / (w[0] + w[1] + w[2]);
        idx[q*3+0] = ii[0]; idx[q*3+1] = ii[1]; idx[q*3+2] = ii[2];
        wn[q*3+0] = w[0]*inv; wn[q*3+1] = w[1]*inv; wn[q*3+2] = w[2]*inv;
    }
}

// ---- Phase 3: fused gather-interp + MLP (GEMM1+ReLU+GEMM2) -----------------
// Per block: 64 queries. Gather h[64][384] (bf16) into LDS, GEMM1 vs W1t
// (K=384, N=256) -> ReLU -> hid LDS (bf16), GEMM2 vs W2t (K=256, N=256) -> out.
// 512 thr = 8 waves (2m x 4n), per-wave output 32x64. Weight tiles are
// register-prefetched one K-iter ahead so L2 latency hides under MFMA.
// LDS: 50.2K (h) + 33.8K (hid) + 20.5K (Bs) + 1.5K = ~104 KB -> 1 block/CU,
// grid = 256 = exactly one block per CU.
__global__ __launch_bounds__(512) void fused_mlp_kernel(
        const float* __restrict__ x, const float* __restrict__ x_skip,
        const int* __restrict__ idx, const float* __restrict__ wnorm,
        const __bf16* __restrict__ W1t, const __bf16* __restrict__ W2t,
        const float* __restrict__ b1, const float* __restrict__ b2,
        float* __restrict__ out) {
    __shared__ __bf16 h[64][392];      // pad 384->392: 784B row, 16B-aligned, 2-way banks
    __shared__ __bf16 hid[64][264];    // pad 256->264: 528B row, 16B-aligned, 2-way banks
    __shared__ __bf16 Bs[256][40];     // weight K-tile 256x32, pad 32->40
    __shared__ int   idxL[192];
    __shared__ float wnL[192];

    const int t  = threadIdx.x;
    const int m0 = blockIdx.x * 64;

    if (t < 192) { idxL[t] = idx[m0*3 + t]; wnL[t] = wnorm[m0*3 + t]; }
    __syncthreads();

    // gather-interpolate: 64 rows x 128 float2 granules (cols 0..255)
    #pragma unroll 4
    for (int p = 0; p < 16; ++p) {
        const int g = p * 512 + t;              // 0..8191
        const int r = g >> 7, c = (g & 127) * 2;
        const int   i0 = idxL[r*3+0], i1 = idxL[r*3+1], i2 = idxL[r*3+2];
        const float w0 = wnL[r*3+0],  w1 = wnL[r*3+1],  w2 = wnL[r*3+2];
        const float2 v0 = *(const float2*)(x + (size_t)i0 * C_IN + c);
        const float2 v1 = *(const float2*)(x + (size_t)i1 * C_IN + c);
        const float2 v2 = *(const float2*)(x + (size_t)i2 * C_IN + c);
        __hip_bfloat162 o;
        o.x = __float2bfloat16(w0*v0.x + w1*v1.x + w2*v2.x);
        o.y = __float2bfloat16(w0*v0.y + w1*v1.y + w2*v2.y);
        *(__hip_bfloat162*)&h[r][c] = o;
    }
    // skip concat: 64 rows x 64 float2 granules (cols 256..383)
    #pragma unroll 4
    for (int p = 0; p < 8; ++p) {
        const int g = p * 512 + t;              // 0..4095
        const int r = g >> 6, c = (g & 63) * 2;
        const float2 v = *(const float2*)(x_skip + (size_t)(m0 + r) * C_SKIP + c);
        __hip_bfloat162 o;
        o.x = __float2bfloat16(v.x);
        o.y = __float2bfloat16(v.y);
        *(__hip_bfloat162*)&h[r][C_IN + c] = o;
    }

    const int wave = t >> 6, lane = t & 63;
    const int ln = lane & 15, kq = lane >> 4;
    const int wm = (wave >> 2) * 32;        // 2 wave-rows of 32
    const int wnc = (wave & 3) * 64;        // 4 wave-cols of 64

    // weight staging coords: 1024 16B-granules per K-tile, 2 per thread
    const int brow0 = t >> 2,          bcol0 = (t & 3) * 8;
    const int brow1 = (512 + t) >> 2,  bcol1 = ((512 + t) & 3) * 8;

    f32x4 acc[2][4] = {};
    int4 breg0, breg1;

    // ---- stage 1: hid = relu(h @ W1t^T + b1), K = 384 ----
    breg0 = *(const int4*)(W1t + (size_t)brow0 * C_H + bcol0);
    breg1 = *(const int4*)(W1t + (size_t)brow1 * C_H + bcol1);
    for (int k0 = 0; k0 < C_H; k0 += 32) {
        __syncthreads();                       // prev-iter Bs reads done (k0=0: gather done)
        *(int4*)&Bs[brow0][bcol0] = breg0;
        *(int4*)&Bs[brow1][bcol1] = breg1;
        __syncthreads();
        if (k0 + 32 < C_H) {                   // prefetch next W1 tile...
            breg0 = *(const int4*)(W1t + (size_t)brow0 * C_H + (k0 + 32) + bcol0);
            breg1 = *(const int4*)(W1t + (size_t)brow1 * C_H + (k0 + 32) + bcol1);
        } else {                               // ...or first W2 tile
            breg0 = *(const int4*)(W2t + (size_t)brow0 * HDIM + bcol0);
            breg1 = *(const int4*)(W2t + (size_t)brow1 * HDIM + bcol1);
        }
        bf16x8 af[2], bfr[4];
        #pragma unroll
        for (int mt = 0; mt < 2; ++mt)
            af[mt] = *(const bf16x8*)&h[wm + mt*16 + ln][k0 + kq*8];
        #pragma unroll
        for (int nt = 0; nt < 4; ++nt)
            bfr[nt] = *(const bf16x8*)&Bs[wnc + nt*16 + ln][kq*8];
        #pragma unroll
        for (int mt = 0; mt < 2; ++mt)
            #pragma unroll
            for (int nt = 0; nt < 4; ++nt)
                acc[mt][nt] = __builtin_amdgcn_mfma_f32_16x16x32_bf16(
                                  af[mt], bfr[nt], acc[mt][nt], 0, 0, 0);
    }

    // stage-1 epilogue: bias + relu -> hid (LDS), reset acc
    #pragma unroll
    for (int nt = 0; nt < 4; ++nt) {
        const int n = wnc + nt*16 + ln;
        const float bv = b1[n];
        #pragma unroll
        for (int mt = 0; mt < 2; ++mt) {
            const int rbase = wm + mt*16 + kq*4;
            #pragma unroll
            for (int r = 0; r < 4; ++r) {
                const float v = fmaxf(acc[mt][nt][r] + bv, 0.0f);
                hid[rbase + r][n] = (__bf16)__float2bfloat16(v);
                acc[mt][nt][r] = 0.0f;
            }
        }
    }

    // ---- stage 2: out = hid @ W2t^T + b2, K = 256 ----
    for (int k0 = 0; k0 < HDIM; k0 += 32) {
        __syncthreads();                       // hid writes visible + stage-1 Bs reads done
        *(int4*)&Bs[brow0][bcol0] = breg0;
        *(int4*)&Bs[brow1][bcol1] = breg1;
        __syncthreads();
        if (k0 + 32 < HDIM) {
            breg0 = *(const int4*)(W2t + (size_t)brow0 * HDIM + (k0 + 32) + bcol0);
            breg1 = *(const int4*)(W2t + (size_t)brow1 * HDIM + (k0 + 32) + bcol1);
        }
        bf16x8 af[2], bfr[4];
        #pragma unroll
        for (int mt = 0; mt < 2; ++mt)
            af[mt] = *(const bf16x8*)&hid[wm + mt*16 + ln][k0 + kq*8];
        #pragma unroll
        for (int nt = 0; nt < 4; ++nt)
            bfr[nt] = *(const bf16x8*)&Bs[wnc + nt*16 + ln][kq*8];
        #pragma unroll
        for (int mt = 0; mt < 2; ++mt)
            #pragma unroll
            for (int nt = 0; nt < 4; ++nt)
                acc[mt][nt] = __builtin_amdgcn_mfma_f32_16x16x32_bf16(
                                  af[mt], bfr[nt], acc[mt][nt], 0, 0, 0);
    }

    // stage-2 epilogue: bias -> out (fp32)
    #pragma unroll
    for (int nt = 0; nt < 4; ++nt) {
        const int n = wnc + nt*16 + ln;
        const float bv = b2[n];
        #pragma unroll
        for (int mt = 0; mt < 2; ++mt) {
            const int rbase = m0 + wm + mt*16 + kq*4;
            #pragma unroll
            for (int r = 0; r < 4; ++r)
                out[(size_t)(rbase + r) * HDIM + n] = acc[mt][nt][r] + bv;
        }
    }
}

extern "C" void kernel_launch(void* const* d_in, const int* in_sizes, int n_in,
                              void* d_out, int out_size, void* d_ws, size_t ws_size,
                              hipStream_t stream) {
    (void)in_sizes; (void)n_in; (void)ws_size;
    const float* x        = (const float*)d_in[0];   // [4096,256]
    const float* pos      = (const float*)d_in[1];   // [4096,3]
    const float* x_skip   = (const float*)d_in[3];   // [16384,128]
    const float* pos_skip = (const float*)d_in[4];   // [16384,3]
    const float* W1       = (const float*)d_in[6];   // [384,256]
    const float* b1       = (const float*)d_in[7];   // [256]
    const float* W2       = (const float*)d_in[8];   // [256,256]
    const float* b2       = (const float*)d_in[9];   // [256]
    float* out = (float*)d_out;

    char* ws = (char*)d_ws;
    float*          cand_d = (float*)(ws);                    // 3*16*M*4 = 3,145,728
    int*            cand_i = (int*)  (ws + 3145728);          // 3,145,728
    int*            idx    = (int*)  (ws + 6291456);          //   196,608
    float*          wn     = (float*)(ws + 6488064);          //   196,608
    __hip_bfloat16* W1t    = (__hip_bfloat16*)(ws + 6684672); //   196,608
    __hip_bfloat16* W2t    = (__hip_bfloat16*)(ws + 6881280); //   131,072
    float4*         pos4   = (float4*)(ws + 7012352);         //    65,536
                                                              // total ~7.1 MB

    prep_tail_kernel<<<(C_H*HDIM + HDIM*HDIM + N_PTS + 255)/256, 256, 0, stream>>>(
        W1, W2, pos, pos_skip, W1t, W2t, pos4, out, out_size);
    knn_part_kernel <<<dim3(M_Q/256, NSPLIT), 256, 0, stream>>>(pos4, pos_skip, cand_d, cand_i);
    knn_merge_kernel<<<M_Q*4/256, 256, 0, stream>>>(cand_d, cand_i, pos, pos_skip, idx, wn);
    fused_mlp_kernel<<<M_Q/64, 512, 0, stream>>>(
        x, x_skip, idx, wn, (const __bf16*)W1t, (const __bf16*)W2t, b1, b2, out);
}

// Round 2
// 147.624 us; speedup vs baseline: 1.1053x; 1.0244x over previous
//
#include <hip/hip_runtime.h>
#include <hip/hip_bf16.h>

#define N_PTS  4096
#define M_Q    16384
#define C_IN   256
#define C_SKIP 128
#define C_H    384      // C_IN + C_SKIP
#define HDIM   256

typedef __bf16 bf16x8 __attribute__((ext_vector_type(8)));
typedef float  f32x4  __attribute__((ext_vector_type(4)));

__device__ __forceinline__ void insert3(float d, int j,
                                        float& b0, float& b1, float& b2,
                                        int& i0, int& i1, int& i2) {
    if (d < b2) {
        if (d < b1) {
            b2 = b1; i2 = i1;
            if (d < b0) { b1 = b0; i1 = i0; b0 = d; i0 = j; }
            else        { b1 = d;  i1 = j; }
        } else { b2 = d; i2 = j; }
    }
}

// ---- Phase 0: fused prep — W1/W2 convert+transpose, pos4 build, out tail ---
__global__ __launch_bounds__(256) void prep_tail_kernel(
        const float* __restrict__ W1, const float* __restrict__ W2,
        const float* __restrict__ pos, const float* __restrict__ pos_skip,
        __hip_bfloat16* __restrict__ W1t, __hip_bfloat16* __restrict__ W2t,
        float4* __restrict__ pos4, float* __restrict__ out, int out_size) {
    const int i = blockIdx.x * 256 + threadIdx.x;
    if (i < C_H * HDIM) {
        const int k = i / HDIM, n = i % HDIM;
        W1t[n * C_H + k] = __float2bfloat16(W1[i]);
    } else if (i < C_H * HDIM + HDIM * HDIM) {
        const int j = i - C_H * HDIM;
        const int k = j / HDIM, n = j % HDIM;
        W2t[n * HDIM + k] = __float2bfloat16(W2[j]);
    } else if (i < C_H * HDIM + HDIM * HDIM + N_PTS) {
        const int j = i - (C_H * HDIM + HDIM * HDIM);
        const float px = pos[j*3+0], py = pos[j*3+1], pz = pos[j*3+2];
        pos4[j] = make_float4(px, py, pz, px*px + py*py + pz*pz);
    }
    // output tail: pos_skip passthrough + zero pad (runs before mega writes)
    if (i < M_Q * 3) out[(size_t)M_Q * HDIM + i] = pos_skip[i];
    const int zbase = M_Q * HDIM + M_Q * 3;
    if (zbase + i < out_size) out[zbase + i] = 0.0f;
}

// ---- Mega kernel: per block = 64 queries: kNN + merge + interp + MLP -------
// 512 thr = 8 waves. kNN: wave w scans points [w*512,(w+1)*512) for all 64
// queries (lane = query), wave-uniform point stream via readfirstlane ->
// scalar s_load path. Branch-free top-3 values via fmed3/min (3 VALU),
// indices via cmp+cndmask. Cross-wave merge through LDS (wave 0), then
// gather-interp h[64][384] -> GEMM1 -> ReLU -> hid -> GEMM2 -> out.
// LDS ~115.5 KB -> 1 block/CU, grid = 256 = one block per CU.
__global__ __launch_bounds__(512) void mega_kernel(
        const float4* __restrict__ pos4, const float* __restrict__ pos_skip,
        const float* __restrict__ x, const float* __restrict__ x_skip,
        const __bf16* __restrict__ W1t, const __bf16* __restrict__ W2t,
        const float* __restrict__ b1, const float* __restrict__ b2,
        float* __restrict__ out) {
    __shared__ __bf16 h[64][392];      // pad 384->392: 784B row, 2-way banks
    __shared__ __bf16 hid[64][264];    // pad 256->264: 528B row, 2-way banks
    __shared__ __bf16 Bs[256][40];     // weight K-tile 256x32, pad 32->40
    __shared__ float candD[8][64][3];
    __shared__ int   candI[8][64][3];
    __shared__ int   idxL[192];
    __shared__ float wnL[192];

    const int t    = threadIdx.x;
    const int m0   = blockIdx.x * 64;
    const int wave = t >> 6, lane = t & 63;

    // ---- kNN phase: wave-split over points, lane = query ----
    {
        const int q = m0 + lane;
        const float m2x = -2.0f * pos_skip[q*3+0];
        const float m2y = -2.0f * pos_skip[q*3+1];
        const float m2z = -2.0f * pos_skip[q*3+2];
        float bb0 = 3e38f, bb1 = 3e38f, bb2 = 3e38f;
        int   ii0 = 0, ii1 = 0, ii2 = 0;
        const int j0 = __builtin_amdgcn_readfirstlane(wave * (N_PTS / 8));
        #pragma unroll 8
        for (int j = 0; j < N_PTS / 8; ++j) {
            const float4 p = pos4[j0 + j];   // uniform -> SGPR broadcast
            const float d = fmaf(p.x, m2x, fmaf(p.y, m2y, fmaf(p.z, m2z, p.w)));
            const int  jj = j0 + j;
            const bool c0 = d < bb0, c1 = d < bb1, c2 = d < bb2;
            ii2 = c2 ? (c1 ? ii1 : jj) : ii2;
            ii1 = c1 ? (c0 ? ii0 : jj) : ii1;
            ii0 = c0 ? jj : ii0;
            bb2 = __builtin_amdgcn_fmed3f(d, bb1, bb2);  // branch-free top-3 values
            bb1 = __builtin_amdgcn_fmed3f(d, bb0, bb1);
            bb0 = fminf(bb0, d);
        }
        candD[wave][lane][0] = bb0; candD[wave][lane][1] = bb1; candD[wave][lane][2] = bb2;
        candI[wave][lane][0] = ii0; candI[wave][lane][1] = ii1; candI[wave][lane][2] = ii2;
    }
    __syncthreads();

    // ---- merge 24 candidates/query (wave 0, lane = query) ----
    if (t < 64) {
        float B0 = 3e38f, B1 = 3e38f, B2 = 3e38f;
        int   I0 = 0, I1 = 0, I2 = 0;
        #pragma unroll
        for (int ww = 0; ww < 8; ++ww) {     // ascending wave = ascending index, tie-break safe
            insert3(candD[ww][t][0], candI[ww][t][0], B0,B1,B2, I0,I1,I2);
            insert3(candD[ww][t][1], candI[ww][t][1], B0,B1,B2, I0,I1,I2);
            insert3(candD[ww][t][2], candI[ww][t][2], B0,B1,B2, I0,I1,I2);
        }
        const int q = m0 + t;
        const float qx = pos_skip[q*3+0], qy = pos_skip[q*3+1], qz = pos_skip[q*3+2];
        float wts[3]; const int ii[3] = {I0, I1, I2};
        #pragma unroll
        for (int r = 0; r < 3; ++r) {
            const float4 p = pos4[ii[r]];
            const float dx = qx - p.x, dy = qy - p.y, dz = qz - p.z;
            const float d2 = dx*dx + dy*dy + dz*dz;   // exact recompute, like reference d2k
            wts[r] = 1.0f / fmaxf(d2, 1e-16f);
        }
        const float inv = 1.0f / (wts[0] + wts[1] + wts[2]);
        idxL[t*3+0] = ii[0]; idxL[t*3+1] = ii[1]; idxL[t*3+2] = ii[2];
        wnL[t*3+0] = wts[0]*inv; wnL[t*3+1] = wts[1]*inv; wnL[t*3+2] = wts[2]*inv;
    }
    __syncthreads();

    // weight staging coords: 1024 16B-granules per K-tile, 2 per thread
    const int brow0 = t >> 2,          bcol0 = (t & 3) * 8;
    const int brow1 = (512 + t) >> 2,  bcol1 = ((512 + t) & 3) * 8;
    int4 breg0, breg1;
    // issue W1 tile-0 loads early: latency hides under the gather phase
    breg0 = *(const int4*)(W1t + (size_t)brow0 * C_H + bcol0);
    breg1 = *(const int4*)(W1t + (size_t)brow1 * C_H + bcol1);

    // ---- gather-interpolate: 64 rows x 128 float2 granules (cols 0..255) ----
    #pragma unroll 4
    for (int p = 0; p < 16; ++p) {
        const int g = p * 512 + t;              // 0..8191
        const int r = g >> 7, c = (g & 127) * 2;
        const int   i0 = idxL[r*3+0], i1 = idxL[r*3+1], i2 = idxL[r*3+2];
        const float w0 = wnL[r*3+0],  w1 = wnL[r*3+1],  w2 = wnL[r*3+2];
        const float2 v0 = *(const float2*)(x + (size_t)i0 * C_IN + c);
        const float2 v1 = *(const float2*)(x + (size_t)i1 * C_IN + c);
        const float2 v2 = *(const float2*)(x + (size_t)i2 * C_IN + c);
        __hip_bfloat162 o;
        o.x = __float2bfloat16(w0*v0.x + w1*v1.x + w2*v2.x);
        o.y = __float2bfloat16(w0*v0.y + w1*v1.y + w2*v2.y);
        *(__hip_bfloat162*)&h[r][c] = o;
    }
    // skip concat: 64 rows x 64 float2 granules (cols 256..383)
    #pragma unroll 4
    for (int p = 0; p < 8; ++p) {
        const int g = p * 512 + t;              // 0..4095
        const int r = g >> 6, c = (g & 63) * 2;
        const float2 v = *(const float2*)(x_skip + (size_t)(m0 + r) * C_SKIP + c);
        __hip_bfloat162 o;
        o.x = __float2bfloat16(v.x);
        o.y = __float2bfloat16(v.y);
        *(__hip_bfloat162*)&h[r][C_IN + c] = o;
    }

    const int ln = lane & 15, kq = lane >> 4;
    const int wm = (wave >> 2) * 32;        // 2 wave-rows of 32
    const int wnc = (wave & 3) * 64;        // 4 wave-cols of 64

    f32x4 acc[2][4] = {};

    // ---- stage 1: hid = relu(h @ W1t^T + b1), K = 384 ----
    for (int k0 = 0; k0 < C_H; k0 += 32) {
        __syncthreads();                       // prev-iter Bs reads done (k0=0: gather done)
        *(int4*)&Bs[brow0][bcol0] = breg0;
        *(int4*)&Bs[brow1][bcol1] = breg1;
        __syncthreads();
        if (k0 + 32 < C_H) {                   // prefetch next W1 tile...
            breg0 = *(const int4*)(W1t + (size_t)brow0 * C_H + (k0 + 32) + bcol0);
            breg1 = *(const int4*)(W1t + (size_t)brow1 * C_H + (k0 + 32) + bcol1);
        } else {                               // ...or first W2 tile
            breg0 = *(const int4*)(W2t + (size_t)brow0 * HDIM + bcol0);
            breg1 = *(const int4*)(W2t + (size_t)brow1 * HDIM + bcol1);
        }
        bf16x8 af[2], bfr[4];
        #pragma unroll
        for (int mt = 0; mt < 2; ++mt)
            af[mt] = *(const bf16x8*)&h[wm + mt*16 + ln][k0 + kq*8];
        #pragma unroll
        for (int nt = 0; nt < 4; ++nt)
            bfr[nt] = *(const bf16x8*)&Bs[wnc + nt*16 + ln][kq*8];
        #pragma unroll
        for (int mt = 0; mt < 2; ++mt)
            #pragma unroll
            for (int nt = 0; nt < 4; ++nt)
                acc[mt][nt] = __builtin_amdgcn_mfma_f32_16x16x32_bf16(
                                  af[mt], bfr[nt], acc[mt][nt], 0, 0, 0);
    }

    // stage-1 epilogue: bias + relu -> hid (LDS), reset acc
    #pragma unroll
    for (int nt = 0; nt < 4; ++nt) {
        const int n = wnc + nt*16 + ln;
        const float bv = b1[n];
        #pragma unroll
        for (int mt = 0; mt < 2; ++mt) {
            const int rbase = wm + mt*16 + kq*4;
            #pragma unroll
            for (int r = 0; r < 4; ++r) {
                const float v = fmaxf(acc[mt][nt][r] + bv, 0.0f);
                hid[rbase + r][n] = (__bf16)__float2bfloat16(v);
                acc[mt][nt][r] = 0.0f;
            }
        }
    }

    // ---- stage 2: out = hid @ W2t^T + b2, K = 256 ----
    for (int k0 = 0; k0 < HDIM; k0 += 32) {
        __syncthreads();                       // hid writes visible + stage-1 Bs reads done
        *(int4*)&Bs[brow0][bcol0] = breg0;
        *(int4*)&Bs[brow1][bcol1] = breg1;
        __syncthreads();
        if (k0 + 32 < HDIM) {
            breg0 = *(const int4*)(W2t + (size_t)brow0 * HDIM + (k0 + 32) + bcol0);
            breg1 = *(const int4*)(W2t + (size_t)brow1 * HDIM + (k0 + 32) + bcol1);
        }
        bf16x8 af[2], bfr[4];
        #pragma unroll
        for (int mt = 0; mt < 2; ++mt)
            af[mt] = *(const bf16x8*)&hid[wm + mt*16 + ln][k0 + kq*8];
        #pragma unroll
        for (int nt = 0; nt < 4; ++nt)
            bfr[nt] = *(const bf16x8*)&Bs[wnc + nt*16 + ln][kq*8];
        #pragma unroll
        for (int mt = 0; mt < 2; ++mt)
            #pragma unroll
            for (int nt = 0; nt < 4; ++nt)
                acc[mt][nt] = __builtin_amdgcn_mfma_f32_16x16x32_bf16(
                                  af[mt], bfr[nt], acc[mt][nt], 0, 0, 0);
    }

    // stage-2 epilogue: bias -> out (fp32)
    #pragma unroll
    for (int nt = 0; nt < 4; ++nt) {
        const int n = wnc + nt*16 + ln;
        const float bv = b2[n];
        #pragma unroll
        for (int mt = 0; mt < 2; ++mt) {
            const int rbase = m0 + wm + mt*16 + kq*4;
            #pragma unroll
            for (int r = 0; r < 4; ++r)
                out[(size_t)(rbase + r) * HDIM + n] = acc[mt][nt][r] + bv;
        }
    }
}

extern "C" void kernel_launch(void* const* d_in, const int* in_sizes, int n_in,
                              void* d_out, int out_size, void* d_ws, size_t ws_size,
                              hipStream_t stream) {
    (void)in_sizes; (void)n_in; (void)ws_size;
    const float* x        = (const float*)d_in[0];   // [4096,256]
    const float* pos      = (const float*)d_in[1];   // [4096,3]
    const float* x_skip   = (const float*)d_in[3];   // [16384,128]
    const float* pos_skip = (const float*)d_in[4];   // [16384,3]
    const float* W1       = (const float*)d_in[6];   // [384,256]
    const float* b1       = (const float*)d_in[7];   // [256]
    const float* W2       = (const float*)d_in[8];   // [256,256]
    const float* b2       = (const float*)d_in[9];   // [256]
    float* out = (float*)d_out;

    char* ws = (char*)d_ws;
    __hip_bfloat16* W1t  = (__hip_bfloat16*)(ws);           // 196,608
    __hip_bfloat16* W2t  = (__hip_bfloat16*)(ws + 196608);  // 131,072
    float4*         pos4 = (float4*)(ws + 327680);          //  65,536
                                                            // total 384 KB

    prep_tail_kernel<<<(C_H*HDIM + HDIM*HDIM + N_PTS + 255)/256, 256, 0, stream>>>(
        W1, W2, pos, pos_skip, W1t, W2t, pos4, out, out_size);
    mega_kernel<<<M_Q/64, 512, 0, stream>>>(
        pos4, pos_skip, x, x_skip, (const __bf16*)W1t, (const __bf16*)W2t, b1, b2, out);
}

// Round 3
// 143.030 us; speedup vs baseline: 1.1408x; 1.0321x over previous
//
#include <hip/hip_runtime.h>
#include <hip/hip_bf16.h>

#define N_PTS  4096
#define M_Q    16384
#define C_IN   256
#define C_SKIP 128
#define C_H    384      // C_IN + C_SKIP
#define HDIM   256
#define QBLK   32       // queries per block -> 512 blocks -> 2 blocks/CU

typedef __bf16 bf16x8 __attribute__((ext_vector_type(8)));
typedef float  f32x4  __attribute__((ext_vector_type(4)));

__device__ __forceinline__ void insert3(float d, int j,
                                        float& b0, float& b1, float& b2,
                                        int& i0, int& i1, int& i2) {
    if (d < b2) {
        if (d < b1) {
            b2 = b1; i2 = i1;
            if (d < b0) { b1 = b0; i1 = i0; b0 = d; i0 = j; }
            else        { b1 = d;  i1 = j; }
        } else { b2 = d; i2 = j; }
    }
}

// ---- Phase 0: fused prep — W1/W2 convert+transpose, pos4 build, out tail ---
__global__ __launch_bounds__(256) void prep_tail_kernel(
        const float* __restrict__ W1, const float* __restrict__ W2,
        const float* __restrict__ pos, const float* __restrict__ pos_skip,
        __hip_bfloat16* __restrict__ W1t, __hip_bfloat16* __restrict__ W2t,
        float4* __restrict__ pos4, float* __restrict__ out, int out_size) {
    const int i = blockIdx.x * 256 + threadIdx.x;
    if (i < C_H * HDIM) {
        const int k = i / HDIM, n = i % HDIM;
        W1t[n * C_H + k] = __float2bfloat16(W1[i]);
    } else if (i < C_H * HDIM + HDIM * HDIM) {
        const int j = i - C_H * HDIM;
        const int k = j / HDIM, n = j % HDIM;
        W2t[n * HDIM + k] = __float2bfloat16(W2[j]);
    } else if (i < C_H * HDIM + HDIM * HDIM + N_PTS) {
        const int j = i - (C_H * HDIM + HDIM * HDIM);
        const float px = pos[j*3+0], py = pos[j*3+1], pz = pos[j*3+2];
        pos4[j] = make_float4(px, py, pz, px*px + py*py + pz*pz);
    }
    // output tail: pos_skip passthrough + zero pad (runs before mega writes)
    if (i < M_Q * 3) out[(size_t)M_Q * HDIM + i] = pos_skip[i];
    const int zbase = M_Q * HDIM + M_Q * 3;
    if (zbase + i < out_size) out[zbase + i] = 0.0f;
}

// ---- Mega kernel v2: 32 queries/block, 512 blocks = 2 blocks/CU ------------
// 512 thr = 8 waves. kNN: each wave's two 32-lane halves scan disjoint
// 256-point ranges (16 sets total) for the block's 32 queries; merge by
// wave 0 + one shfl_xor(32). MLP: gather h[32][384] -> GEMM1 -> ReLU ->
// hid -> GEMM2 -> out, with weight fragments loaded per-lane directly from
// L2 (no LDS staging, no K-loop barriers), double-prefetched 2 K-steps ahead.
// LDS 55 KB -> 2 blocks/CU (16 waves). 4 barriers total.
__global__ __launch_bounds__(512, 4) void mega_kernel(
        const float4* __restrict__ pos4, const float* __restrict__ pos_skip,
        const float* __restrict__ x, const float* __restrict__ x_skip,
        const __bf16* __restrict__ W1t, const __bf16* __restrict__ W2t,
        const float* __restrict__ b1, const float* __restrict__ b2,
        float* __restrict__ out) {
    __shared__ __bf16 h[QBLK][392];      // pad 384->392: 784B row
    __shared__ __bf16 hid[QBLK][264];    // pad 256->264: 528B row
    __shared__ float candD[16][QBLK][3];
    __shared__ int   candI[16][QBLK][3];
    __shared__ int   idxL[QBLK*3];
    __shared__ float wnL[QBLK*3];

    const int t    = threadIdx.x;
    const int m0   = blockIdx.x * QBLK;
    const int wave = t >> 6, lane = t & 63;
    const int qh   = lane & 31;          // query within block
    const int half = lane >> 5;

    // ---- preload x_skip into regs: latency hides under kNN compute ----
    float2 skipv[4];
    #pragma unroll
    for (int p = 0; p < 4; ++p) {
        const int g = p * 512 + t;                 // 0..2047
        const int r = g >> 6, c = (g & 63) * 2;
        skipv[p] = *(const float2*)(x_skip + (size_t)(m0 + r) * C_SKIP + c);
    }

    // ---- kNN: 16 point-sets of 256; set s = wave*2 + half ----
    const int q = m0 + qh;
    const float qx = pos_skip[q*3+0], qy = pos_skip[q*3+1], qz = pos_skip[q*3+2];
    const float m2x = -2.0f * qx, m2y = -2.0f * qy, m2z = -2.0f * qz;
    {
        const int s  = wave * 2 + half;
        const int j0 = s * (N_PTS / 16);           // 256-point range
        float bb0 = 3e38f, bb1 = 3e38f, bb2 = 3e38f;
        int   ii0 = 0, ii1 = 0, ii2 = 0;
        const float4* pp = pos4 + j0;
        #pragma unroll 8
        for (int j = 0; j < N_PTS / 16; ++j) {
            const float4 p = pp[j];                // 2 distinct addrs/wave, L2-hot
            const float d = fmaf(p.x, m2x, fmaf(p.y, m2y, fmaf(p.z, m2z, p.w)));
            const int  jj = j0 + j;
            const bool c0 = d < bb0, c1 = d < bb1, c2 = d < bb2;
            ii2 = c2 ? (c1 ? ii1 : jj) : ii2;
            ii1 = c1 ? (c0 ? ii0 : jj) : ii1;
            ii0 = c0 ? jj : ii0;
            bb2 = __builtin_amdgcn_fmed3f(d, bb1, bb2);   // branch-free top-3 values
            bb1 = __builtin_amdgcn_fmed3f(d, bb0, bb1);
            bb0 = fminf(bb0, d);
        }
        candD[s][qh][0] = bb0; candD[s][qh][1] = bb1; candD[s][qh][2] = bb2;
        candI[s][qh][0] = ii0; candI[s][qh][1] = ii1; candI[s][qh][2] = ii2;
    }
    // skip-concat writes (independent of kNN results)
    #pragma unroll
    for (int p = 0; p < 4; ++p) {
        const int g = p * 512 + t;
        const int r = g >> 6, c = (g & 63) * 2;
        __hip_bfloat162 o;
        o.x = __float2bfloat16(skipv[p].x);
        o.y = __float2bfloat16(skipv[p].y);
        *(__hip_bfloat162*)&h[r][C_IN + c] = o;
    }
    __syncthreads();

    // ---- merge 48 candidates/query (wave 0; 2 lanes/query + shfl) ----
    if (t < 64) {
        const int mq = t & 31, sb = (t >> 5) * 8;  // ascending set = ascending index
        float B0 = 3e38f, B1 = 3e38f, B2v = 3e38f;
        int   I0 = 0, I1 = 0, I2 = 0;
        #pragma unroll
        for (int s2 = 0; s2 < 8; ++s2) {
            const int ss = sb + s2;
            insert3(candD[ss][mq][0], candI[ss][mq][0], B0,B1,B2v, I0,I1,I2);
            insert3(candD[ss][mq][1], candI[ss][mq][1], B0,B1,B2v, I0,I1,I2);
            insert3(candD[ss][mq][2], candI[ss][mq][2], B0,B1,B2v, I0,I1,I2);
        }
        const float nb0 = __shfl_xor(B0, 32), nb1 = __shfl_xor(B1, 32), nb2 = __shfl_xor(B2v, 32);
        const int   nI0 = __shfl_xor(I0, 32), nI1 = __shfl_xor(I1, 32), nI2 = __shfl_xor(I2, 32);
        if (t < 32) {                              // low half = lower sets = tie-break base
            insert3(nb0, nI0, B0,B1,B2v, I0,I1,I2);
            insert3(nb1, nI1, B0,B1,B2v, I0,I1,I2);
            insert3(nb2, nI2, B0,B1,B2v, I0,I1,I2);
            // exact d2 = surrogate d' + |q|^2 (cancellation bounded: weights clamp at eps)
            const float qq = qx*qx + qy*qy + qz*qz;
            const float w0 = 1.0f / fmaxf(B0  + qq, 1e-16f);
            const float w1 = 1.0f / fmaxf(B1  + qq, 1e-16f);
            const float w2 = 1.0f / fmaxf(B2v + qq, 1e-16f);
            const float inv = 1.0f / (w0 + w1 + w2);
            idxL[mq*3+0] = I0; idxL[mq*3+1] = I1; idxL[mq*3+2] = I2;
            wnL[mq*3+0] = w0*inv; wnL[mq*3+1] = w1*inv; wnL[mq*3+2] = w2*inv;
        }
    }
    __syncthreads();

    // ---- weight fragment pointers (per-lane direct-from-L2, no LDS) ----
    const int ln = lane & 15, kq = lane >> 4;
    const __bf16* w1p0 = W1t + (size_t)(wave*32 +      ln) * C_H  + kq*8;
    const __bf16* w1p1 = W1t + (size_t)(wave*32 + 16 + ln) * C_H  + kq*8;
    const __bf16* w2p0 = W2t + (size_t)(wave*32 +      ln) * HDIM + kq*8;
    const __bf16* w2p1 = W2t + (size_t)(wave*32 + 16 + ln) * HDIM + kq*8;
    bf16x8 wa0, wa1, wb0, wb1;
    wa0 = *(const bf16x8*)(w1p0);      wa1 = *(const bf16x8*)(w1p1);
    wb0 = *(const bf16x8*)(w1p0 + 32); wb1 = *(const bf16x8*)(w1p1 + 32);

    // ---- gather-interpolate: 32 rows x 128 float2 granules (cols 0..255) ----
    #pragma unroll 4
    for (int p = 0; p < 8; ++p) {
        const int g = p * 512 + t;                 // 0..4095
        const int r = g >> 7, c = (g & 127) * 2;
        const int   i0 = idxL[r*3+0], i1 = idxL[r*3+1], i2 = idxL[r*3+2];
        const float w0 = wnL[r*3+0],  w1 = wnL[r*3+1],  w2 = wnL[r*3+2];
        const float2 v0 = *(const float2*)(x + (size_t)i0 * C_IN + c);
        const float2 v1 = *(const float2*)(x + (size_t)i1 * C_IN + c);
        const float2 v2 = *(const float2*)(x + (size_t)i2 * C_IN + c);
        __hip_bfloat162 o;
        o.x = __float2bfloat16(w0*v0.x + w1*v1.x + w2*v2.x);
        o.y = __float2bfloat16(w0*v0.y + w1*v1.y + w2*v2.y);
        *(__hip_bfloat162*)&h[r][c] = o;
    }
    __syncthreads();

    f32x4 acc[2][2] = {};

    // ---- stage 1: hid = relu(h @ W1t^T + b1), K=384, barrier-free ----
    #pragma unroll
    for (int k0 = 0; k0 < C_H; k0 += 64) {
        // half A: k0, uses wa
        bf16x8 af0 = *(const bf16x8*)&h[     ln][k0 + kq*8];
        bf16x8 af1 = *(const bf16x8*)&h[16 + ln][k0 + kq*8];
        acc[0][0] = __builtin_amdgcn_mfma_f32_16x16x32_bf16(af0, wa0, acc[0][0], 0,0,0);
        acc[0][1] = __builtin_amdgcn_mfma_f32_16x16x32_bf16(af0, wa1, acc[0][1], 0,0,0);
        acc[1][0] = __builtin_amdgcn_mfma_f32_16x16x32_bf16(af1, wa0, acc[1][0], 0,0,0);
        acc[1][1] = __builtin_amdgcn_mfma_f32_16x16x32_bf16(af1, wa1, acc[1][1], 0,0,0);
        if (k0 + 64 < C_H) { wa0 = *(const bf16x8*)(w1p0 + k0+64); wa1 = *(const bf16x8*)(w1p1 + k0+64); }
        else               { wa0 = *(const bf16x8*)(w2p0);         wa1 = *(const bf16x8*)(w2p1); }
        // half B: k0+32, uses wb
        bf16x8 bf0 = *(const bf16x8*)&h[     ln][k0+32 + kq*8];
        bf16x8 bf1 = *(const bf16x8*)&h[16 + ln][k0+32 + kq*8];
        acc[0][0] = __builtin_amdgcn_mfma_f32_16x16x32_bf16(bf0, wb0, acc[0][0], 0,0,0);
        acc[0][1] = __builtin_amdgcn_mfma_f32_16x16x32_bf16(bf0, wb1, acc[0][1], 0,0,0);
        acc[1][0] = __builtin_amdgcn_mfma_f32_16x16x32_bf16(bf1, wb0, acc[1][0], 0,0,0);
        acc[1][1] = __builtin_amdgcn_mfma_f32_16x16x32_bf16(bf1, wb1, acc[1][1], 0,0,0);
        if (k0 + 96 < C_H) { wb0 = *(const bf16x8*)(w1p0 + k0+96); wb1 = *(const bf16x8*)(w1p1 + k0+96); }
        else               { wb0 = *(const bf16x8*)(w2p0 + (k0+96-C_H)); wb1 = *(const bf16x8*)(w2p1 + (k0+96-C_H)); }
    }

    // stage-1 epilogue: bias + relu -> hid (LDS), reset acc
    #pragma unroll
    for (int nt = 0; nt < 2; ++nt) {
        const int n = wave*32 + nt*16 + ln;
        const float bv = b1[n];
        #pragma unroll
        for (int mt = 0; mt < 2; ++mt) {
            const int rbase = mt*16 + kq*4;
            #pragma unroll
            for (int r = 0; r < 4; ++r) {
                const float v = fmaxf(acc[mt][nt][r] + bv, 0.0f);
                hid[rbase + r][n] = (__bf16)__float2bfloat16(v);
                acc[mt][nt][r] = 0.0f;
            }
        }
    }
    __syncthreads();

    // ---- stage 2: out = hid @ W2t^T + b2, K=256, barrier-free ----
    #pragma unroll
    for (int k0 = 0; k0 < HDIM; k0 += 64) {
        bf16x8 af0 = *(const bf16x8*)&hid[     ln][k0 + kq*8];
        bf16x8 af1 = *(const bf16x8*)&hid[16 + ln][k0 + kq*8];
        acc[0][0] = __builtin_amdgcn_mfma_f32_16x16x32_bf16(af0, wa0, acc[0][0], 0,0,0);
        acc[0][1] = __builtin_amdgcn_mfma_f32_16x16x32_bf16(af0, wa1, acc[0][1], 0,0,0);
        acc[1][0] = __builtin_amdgcn_mfma_f32_16x16x32_bf16(af1, wa0, acc[1][0], 0,0,0);
        acc[1][1] = __builtin_amdgcn_mfma_f32_16x16x32_bf16(af1, wa1, acc[1][1], 0,0,0);
        if (k0 + 64 < HDIM) { wa0 = *(const bf16x8*)(w2p0 + k0+64); wa1 = *(const bf16x8*)(w2p1 + k0+64); }
        bf16x8 bf0 = *(const bf16x8*)&hid[     ln][k0+32 + kq*8];
        bf16x8 bf1 = *(const bf16x8*)&hid[16 + ln][k0+32 + kq*8];
        acc[0][0] = __builtin_amdgcn_mfma_f32_16x16x32_bf16(bf0, wb0, acc[0][0], 0,0,0);
        acc[0][1] = __builtin_amdgcn_mfma_f32_16x16x32_bf16(bf0, wb1, acc[0][1], 0,0,0);
        acc[1][0] = __builtin_amdgcn_mfma_f32_16x16x32_bf16(bf1, wb0, acc[1][0], 0,0,0);
        acc[1][1] = __builtin_amdgcn_mfma_f32_16x16x32_bf16(bf1, wb1, acc[1][1], 0,0,0);
        if (k0 + 96 < HDIM) { wb0 = *(const bf16x8*)(w2p0 + k0+96); wb1 = *(const bf16x8*)(w2p1 + k0+96); }
    }

    // stage-2 epilogue: bias -> out (fp32)
    #pragma unroll
    for (int nt = 0; nt < 2; ++nt) {
        const int n = wave*32 + nt*16 + ln;
        const float bv = b2[n];
        #pragma unroll
        for (int mt = 0; mt < 2; ++mt) {
            const int rbase = m0 + mt*16 + kq*4;
            #pragma unroll
            for (int r = 0; r < 4; ++r)
                out[(size_t)(rbase + r) * HDIM + n] = acc[mt][nt][r] + bv;
        }
    }
}

extern "C" void kernel_launch(void* const* d_in, const int* in_sizes, int n_in,
                              void* d_out, int out_size, void* d_ws, size_t ws_size,
                              hipStream_t stream) {
    (void)in_sizes; (void)n_in; (void)ws_size;
    const float* x        = (const float*)d_in[0];   // [4096,256]
    const float* pos      = (const float*)d_in[1];   // [4096,3]
    const float* x_skip   = (const float*)d_in[3];   // [16384,128]
    const float* pos_skip = (const float*)d_in[4];   // [16384,3]
    const float* W1       = (const float*)d_in[6];   // [384,256]
    const float* b1       = (const float*)d_in[7];   // [256]
    const float* W2       = (const float*)d_in[8];   // [256,256]
    const float* b2       = (const float*)d_in[9];   // [256]
    float* out = (float*)d_out;

    char* ws = (char*)d_ws;
    __hip_bfloat16* W1t  = (__hip_bfloat16*)(ws);           // 196,608
    __hip_bfloat16* W2t  = (__hip_bfloat16*)(ws + 196608);  // 131,072
    float4*         pos4 = (float4*)(ws + 327680);          //  65,536
                                                            // total 384 KB

    prep_tail_kernel<<<(C_H*HDIM + HDIM*HDIM + N_PTS + 255)/256, 256, 0, stream>>>(
        W1, W2, pos, pos_skip, W1t, W2t, pos4, out, out_size);
    mega_kernel<<<M_Q/QBLK, 512, 0, stream>>>(
        pos4, pos_skip, x, x_skip, (const __bf16*)W1t, (const __bf16*)W2t, b1, b2, out);
}

// Round 4
// 142.571 us; speedup vs baseline: 1.1445x; 1.0032x over previous
//
#include <hip/hip_runtime.h>
#include <hip/hip_bf16.h>

#define N_PTS  4096
#define M_Q    16384
#define C_IN   256
#define C_SKIP 128
#define C_H    384      // C_IN + C_SKIP
#define HDIM   256
#define QA     64       // queries per knn block  -> 256 blocks
#define QBLK   32       // queries per mlp block  -> 512 blocks, 2/CU

typedef __bf16 bf16x8 __attribute__((ext_vector_type(8)));
typedef float  f32x4  __attribute__((ext_vector_type(4)));

__device__ __forceinline__ void insert3(float d, int j,
                                        float& b0, float& b1, float& b2,
                                        int& i0, int& i1, int& i2) {
    if (d < b2) {
        if (d < b1) {
            b2 = b1; i2 = i1;
            if (d < b0) { b1 = b0; i1 = i0; b0 = d; i0 = j; }
            else        { b1 = d;  i1 = j; }
        } else { b2 = d; i2 = j; }
    }
}

// ---- Phase 0: fused prep — W1/W2 convert+transpose, pos4 build, out tail ---
__global__ __launch_bounds__(256) void prep_tail_kernel(
        const float* __restrict__ W1, const float* __restrict__ W2,
        const float* __restrict__ pos, const float* __restrict__ pos_skip,
        __hip_bfloat16* __restrict__ W1t, __hip_bfloat16* __restrict__ W2t,
        float4* __restrict__ pos4, float* __restrict__ out, int out_size) {
    const int i = blockIdx.x * 256 + threadIdx.x;
    if (i < C_H * HDIM) {
        const int k = i / HDIM, n = i % HDIM;
        W1t[n * C_H + k] = __float2bfloat16(W1[i]);
    } else if (i < C_H * HDIM + HDIM * HDIM) {
        const int j = i - C_H * HDIM;
        const int k = j / HDIM, n = j % HDIM;
        W2t[n * HDIM + k] = __float2bfloat16(W2[j]);
    } else if (i < C_H * HDIM + HDIM * HDIM + N_PTS) {
        const int j = i - (C_H * HDIM + HDIM * HDIM);
        const float px = pos[j*3+0], py = pos[j*3+1], pz = pos[j*3+2];
        pos4[j] = make_float4(px, py, pz, px*px + py*py + pz*pz);
    }
    // output tail: pos_skip passthrough + zero pad (runs before mlp writes)
    if (i < M_Q * 3) out[(size_t)M_Q * HDIM + i] = pos_skip[i];
    const int zbase = M_Q * HDIM + M_Q * 3;
    if (zbase + i < out_size) out[zbase + i] = 0.0f;
}

// ---- Kernel A: kNN via LDS-broadcast point stream --------------------------
// 64 queries/block, 512 thr = 8 waves, lane = query. All 4096 pos4 staged to
// LDS (64 KB); wave w scans points [w*512,(w+1)*512) with wave-uniform
// ds_read_b128 (LDS broadcast: no VMEM, no TA cost, offset-immediate under
// unroll). Merge 24 cands/query by wave 0; weights from surrogate d' + |q|^2.
// LDS 76 KB. Expected VALU-issue-bound: ~16 instr/pair.
__global__ __launch_bounds__(512) void knn_kernel(
        const float4* __restrict__ pos4, const float* __restrict__ pos_skip,
        int* __restrict__ idx, float* __restrict__ wn) {
    __shared__ float4 posL[N_PTS];       // 64 KB
    __shared__ float candD[8][QA][3];    // 6 KB
    __shared__ int   candI[8][QA][3];    // 6 KB

    const int t    = threadIdx.x;
    const int m0   = blockIdx.x * QA;
    const int wave = t >> 6, lane = t & 63;

    // stage all points (coalesced, 8 float4 per thread)
    #pragma unroll
    for (int k = 0; k < N_PTS / 512; ++k)
        posL[k * 512 + t] = pos4[k * 512 + t];

    const int q = m0 + lane;
    const float qx = pos_skip[q*3+0], qy = pos_skip[q*3+1], qz = pos_skip[q*3+2];
    const float m2x = -2.0f * qx, m2y = -2.0f * qy, m2z = -2.0f * qz;
    __syncthreads();

    {
        const int j0 = wave * (N_PTS / 8);     // 512-point range, wave-uniform
        float bb0 = 3e38f, bb1 = 3e38f, bb2 = 3e38f;
        int   ii0 = 0, ii1 = 0, ii2 = 0;
        #pragma unroll 8
        for (int j = 0; j < N_PTS / 8; ++j) {
            const float4 p = posL[j0 + j];     // uniform addr -> LDS broadcast
            const float d = fmaf(p.x, m2x, fmaf(p.y, m2y, fmaf(p.z, m2z, p.w)));
            const int  jj = j0 + j;
            const bool c0 = d < bb0, c1 = d < bb1, c2 = d < bb2;
            ii2 = c2 ? (c1 ? ii1 : jj) : ii2;
            ii1 = c1 ? (c0 ? ii0 : jj) : ii1;
            ii0 = c0 ? jj : ii0;
            bb2 = __builtin_amdgcn_fmed3f(d, bb1, bb2);  // branch-free top-3 values
            bb1 = __builtin_amdgcn_fmed3f(d, bb0, bb1);
            bb0 = fminf(bb0, d);
        }
        candD[wave][lane][0] = bb0; candD[wave][lane][1] = bb1; candD[wave][lane][2] = bb2;
        candI[wave][lane][0] = ii0; candI[wave][lane][1] = ii1; candI[wave][lane][2] = ii2;
    }
    __syncthreads();

    // merge 24 candidates/query (wave 0, lane = query; ascending wave = ascending j)
    if (t < 64) {
        float B0 = 3e38f, B1 = 3e38f, B2v = 3e38f;
        int   I0 = 0, I1 = 0, I2 = 0;
        #pragma unroll
        for (int ww = 0; ww < 8; ++ww) {
            insert3(candD[ww][t][0], candI[ww][t][0], B0,B1,B2v, I0,I1,I2);
            insert3(candD[ww][t][1], candI[ww][t][1], B0,B1,B2v, I0,I1,I2);
            insert3(candD[ww][t][2], candI[ww][t][2], B0,B1,B2v, I0,I1,I2);
        }
        // exact d2 = surrogate d' + |q|^2 (verified in rounds 2-3)
        const float qq = qx*qx + qy*qy + qz*qz;
        const float w0 = 1.0f / fmaxf(B0  + qq, 1e-16f);
        const float w1 = 1.0f / fmaxf(B1  + qq, 1e-16f);
        const float w2 = 1.0f / fmaxf(B2v + qq, 1e-16f);
        const float inv = 1.0f / (w0 + w1 + w2);
        idx[q*3+0] = I0; idx[q*3+1] = I1; idx[q*3+2] = I2;
        wn[q*3+0] = w0*inv; wn[q*3+1] = w1*inv; wn[q*3+2] = w2*inv;
    }
}

// ---- Kernel B: gather-interp + MLP (GEMM1+ReLU+GEMM2) ----------------------
// 32 queries/block, 512 blocks = 2/CU. Gather h[32][384] (float4 loads ->
// half the VMEM instrs), GEMM1 -> ReLU -> hid -> GEMM2 -> out. Weight
// fragments per-lane direct from L2 (no LDS staging, barrier-free K-loops),
// double-prefetched. LDS ~43 KB.
__global__ __launch_bounds__(512, 4) void mlp_kernel(
        const float* __restrict__ x, const float* __restrict__ x_skip,
        const int* __restrict__ idx, const float* __restrict__ wnorm,
        const __bf16* __restrict__ W1t, const __bf16* __restrict__ W2t,
        const float* __restrict__ b1, const float* __restrict__ b2,
        float* __restrict__ out) {
    __shared__ __bf16 h[QBLK][392];      // pad 384->392
    __shared__ __bf16 hid[QBLK][264];    // pad 256->264
    __shared__ int   idxL[QBLK*3];
    __shared__ float wnL[QBLK*3];

    const int t    = threadIdx.x;
    const int m0   = blockIdx.x * QBLK;
    const int wave = t >> 6, lane = t & 63;

    if (t < 96) { idxL[t] = idx[m0*3 + t]; wnL[t] = wnorm[m0*3 + t]; }

    // ---- weight fragment pointers (per-lane direct-from-L2, no LDS) ----
    const int ln = lane & 15, kq = lane >> 4;
    const __bf16* w1p0 = W1t + (size_t)(wave*32 +      ln) * C_H  + kq*8;
    const __bf16* w1p1 = W1t + (size_t)(wave*32 + 16 + ln) * C_H  + kq*8;
    const __bf16* w2p0 = W2t + (size_t)(wave*32 +      ln) * HDIM + kq*8;
    const __bf16* w2p1 = W2t + (size_t)(wave*32 + 16 + ln) * HDIM + kq*8;
    bf16x8 wa0, wa1, wb0, wb1;
    wa0 = *(const bf16x8*)(w1p0);      wa1 = *(const bf16x8*)(w1p1);
    wb0 = *(const bf16x8*)(w1p0 + 32); wb1 = *(const bf16x8*)(w1p1 + 32);

    // skip concat: 32 rows x 32 float4 granules (cols 256..383), 2/thread
    #pragma unroll
    for (int p = 0; p < 2; ++p) {
        const int g = p * 512 + t;                 // 0..1023
        const int r = g >> 5, c = (g & 31) * 4;
        const float4 v = *(const float4*)(x_skip + (size_t)(m0 + r) * C_SKIP + c);
        __hip_bfloat162 o01, o23;
        o01.x = __float2bfloat16(v.x); o01.y = __float2bfloat16(v.y);
        o23.x = __float2bfloat16(v.z); o23.y = __float2bfloat16(v.w);
        *(__hip_bfloat162*)&h[r][C_IN + c]     = o01;
        *(__hip_bfloat162*)&h[r][C_IN + c + 2] = o23;
    }
    __syncthreads();   // idxL/wnL ready

    // gather-interpolate: 32 rows x 64 float4 granules (cols 0..255), 4/thread
    #pragma unroll 4
    for (int p = 0; p < 4; ++p) {
        const int g = p * 512 + t;                 // 0..2047
        const int r = g >> 6, c = (g & 63) * 4;
        const int   i0 = idxL[r*3+0], i1 = idxL[r*3+1], i2 = idxL[r*3+2];
        const float w0 = wnL[r*3+0],  w1 = wnL[r*3+1],  w2 = wnL[r*3+2];
        const float4 v0 = *(const float4*)(x + (size_t)i0 * C_IN + c);
        const float4 v1 = *(const float4*)(x + (size_t)i1 * C_IN + c);
        const float4 v2 = *(const float4*)(x + (size_t)i2 * C_IN + c);
        __hip_bfloat162 o01, o23;
        o01.x = __float2bfloat16(w0*v0.x + w1*v1.x + w2*v2.x);
        o01.y = __float2bfloat16(w0*v0.y + w1*v1.y + w2*v2.y);
        o23.x = __float2bfloat16(w0*v0.z + w1*v1.z + w2*v2.z);
        o23.y = __float2bfloat16(w0*v0.w + w1*v1.w + w2*v2.w);
        *(__hip_bfloat162*)&h[r][c]     = o01;
        *(__hip_bfloat162*)&h[r][c + 2] = o23;
    }
    __syncthreads();   // h complete

    f32x4 acc[2][2] = {};

    // ---- stage 1: hid = relu(h @ W1t^T + b1), K=384, barrier-free ----
    #pragma unroll
    for (int k0 = 0; k0 < C_H; k0 += 64) {
        bf16x8 af0 = *(const bf16x8*)&h[     ln][k0 + kq*8];
        bf16x8 af1 = *(const bf16x8*)&h[16 + ln][k0 + kq*8];
        acc[0][0] = __builtin_amdgcn_mfma_f32_16x16x32_bf16(af0, wa0, acc[0][0], 0,0,0);
        acc[0][1] = __builtin_amdgcn_mfma_f32_16x16x32_bf16(af0, wa1, acc[0][1], 0,0,0);
        acc[1][0] = __builtin_amdgcn_mfma_f32_16x16x32_bf16(af1, wa0, acc[1][0], 0,0,0);
        acc[1][1] = __builtin_amdgcn_mfma_f32_16x16x32_bf16(af1, wa1, acc[1][1], 0,0,0);
        if (k0 + 64 < C_H) { wa0 = *(const bf16x8*)(w1p0 + k0+64); wa1 = *(const bf16x8*)(w1p1 + k0+64); }
        else               { wa0 = *(const bf16x8*)(w2p0);         wa1 = *(const bf16x8*)(w2p1); }
        bf16x8 bf0 = *(const bf16x8*)&h[     ln][k0+32 + kq*8];
        bf16x8 bf1 = *(const bf16x8*)&h[16 + ln][k0+32 + kq*8];
        acc[0][0] = __builtin_amdgcn_mfma_f32_16x16x32_bf16(bf0, wb0, acc[0][0], 0,0,0);
        acc[0][1] = __builtin_amdgcn_mfma_f32_16x16x32_bf16(bf0, wb1, acc[0][1], 0,0,0);
        acc[1][0] = __builtin_amdgcn_mfma_f32_16x16x32_bf16(bf1, wb0, acc[1][0], 0,0,0);
        acc[1][1] = __builtin_amdgcn_mfma_f32_16x16x32_bf16(bf1, wb1, acc[1][1], 0,0,0);
        if (k0 + 96 < C_H) { wb0 = *(const bf16x8*)(w1p0 + k0+96); wb1 = *(const bf16x8*)(w1p1 + k0+96); }
        else               { wb0 = *(const bf16x8*)(w2p0 + (k0+96-C_H)); wb1 = *(const bf16x8*)(w2p1 + (k0+96-C_H)); }
    }

    // stage-1 epilogue: bias + relu -> hid (LDS), reset acc
    #pragma unroll
    for (int nt = 0; nt < 2; ++nt) {
        const int n = wave*32 + nt*16 + ln;
        const float bv = b1[n];
        #pragma unroll
        for (int mt = 0; mt < 2; ++mt) {
            const int rbase = mt*16 + kq*4;
            #pragma unroll
            for (int r = 0; r < 4; ++r) {
                const float v = fmaxf(acc[mt][nt][r] + bv, 0.0f);
                hid[rbase + r][n] = (__bf16)__float2bfloat16(v);
                acc[mt][nt][r] = 0.0f;
            }
        }
    }
    __syncthreads();

    // ---- stage 2: out = hid @ W2t^T + b2, K=256, barrier-free ----
    #pragma unroll
    for (int k0 = 0; k0 < HDIM; k0 += 64) {
        bf16x8 af0 = *(const bf16x8*)&hid[     ln][k0 + kq*8];
        bf16x8 af1 = *(const bf16x8*)&hid[16 + ln][k0 + kq*8];
        acc[0][0] = __builtin_amdgcn_mfma_f32_16x16x32_bf16(af0, wa0, acc[0][0], 0,0,0);
        acc[0][1] = __builtin_amdgcn_mfma_f32_16x16x32_bf16(af0, wa1, acc[0][1], 0,0,0);
        acc[1][0] = __builtin_amdgcn_mfma_f32_16x16x32_bf16(af1, wa0, acc[1][0], 0,0,0);
        acc[1][1] = __builtin_amdgcn_mfma_f32_16x16x32_bf16(af1, wa1, acc[1][1], 0,0,0);
        if (k0 + 64 < HDIM) { wa0 = *(const bf16x8*)(w2p0 + k0+64); wa1 = *(const bf16x8*)(w2p1 + k0+64); }
        bf16x8 bf0 = *(const bf16x8*)&hid[     ln][k0+32 + kq*8];
        bf16x8 bf1 = *(const bf16x8*)&hid[16 + ln][k0+32 + kq*8];
        acc[0][0] = __builtin_amdgcn_mfma_f32_16x16x32_bf16(bf0, wb0, acc[0][0], 0,0,0);
        acc[0][1] = __builtin_amdgcn_mfma_f32_16x16x32_bf16(bf0, wb1, acc[0][1], 0,0,0);
        acc[1][0] = __builtin_amdgcn_mfma_f32_16x16x32_bf16(bf1, wb0, acc[1][0], 0,0,0);
        acc[1][1] = __builtin_amdgcn_mfma_f32_16x16x32_bf16(bf1, wb1, acc[1][1], 0,0,0);
        if (k0 + 96 < HDIM) { wb0 = *(const bf16x8*)(w2p0 + k0+96); wb1 = *(const bf16x8*)(w2p1 + k0+96); }
    }

    // stage-2 epilogue: bias -> out (fp32)
    #pragma unroll
    for (int nt = 0; nt < 2; ++nt) {
        const int n = wave*32 + nt*16 + ln;
        const float bv = b2[n];
        #pragma unroll
        for (int mt = 0; mt < 2; ++mt) {
            const int rbase = m0 + mt*16 + kq*4;
            #pragma unroll
            for (int r = 0; r < 4; ++r)
                out[(size_t)(rbase + r) * HDIM + n] = acc[mt][nt][r] + bv;
        }
    }
}

extern "C" void kernel_launch(void* const* d_in, const int* in_sizes, int n_in,
                              void* d_out, int out_size, void* d_ws, size_t ws_size,
                              hipStream_t stream) {
    (void)in_sizes; (void)n_in; (void)ws_size;
    const float* x        = (const float*)d_in[0];   // [4096,256]
    const float* pos      = (const float*)d_in[1];   // [4096,3]
    const float* x_skip   = (const float*)d_in[3];   // [16384,128]
    const float* pos_skip = (const float*)d_in[4];   // [16384,3]
    const float* W1       = (const float*)d_in[6];   // [384,256]
    const float* b1       = (const float*)d_in[7];   // [256]
    const float* W2       = (const float*)d_in[8];   // [256,256]
    const float* b2       = (const float*)d_in[9];   // [256]
    float* out = (float*)d_out;

    char* ws = (char*)d_ws;
    __hip_bfloat16* W1t  = (__hip_bfloat16*)(ws);           // 196,608
    __hip_bfloat16* W2t  = (__hip_bfloat16*)(ws + 196608);  // 131,072
    float4*         pos4 = (float4*)(ws + 327680);          //  65,536
    int*            idx  = (int*)  (ws + 393216);           // 196,608
    float*          wn   = (float*)(ws + 589824);           // 196,608
                                                            // total 768 KB

    prep_tail_kernel<<<(C_H*HDIM + HDIM*HDIM + N_PTS + 255)/256, 256, 0, stream>>>(
        W1, W2, pos, pos_skip, W1t, W2t, pos4, out, out_size);
    knn_kernel<<<M_Q/QA, 512, 0, stream>>>(pos4, pos_skip, idx, wn);
    mlp_kernel<<<M_Q/QBLK, 512, 0, stream>>>(
        x, x_skip, idx, wn, (const __bf16*)W1t, (const __bf16*)W2t, b1, b2, out);
}

// Round 5
// 140.354 us; speedup vs baseline: 1.1626x; 1.0158x over previous
//
#include <hip/hip_runtime.h>
#include <hip/hip_bf16.h>

#define N_PTS  4096
#define M_Q    16384
#define C_IN   256
#define C_SKIP 128
#define C_H    384      // C_IN + C_SKIP
#define HDIM   256
#define QB     64       // queries per block -> 256 blocks = 1/CU

typedef __bf16 bf16x8 __attribute__((ext_vector_type(8)));
typedef float  f32x4  __attribute__((ext_vector_type(4)));

__device__ __forceinline__ void insert3(float d, int j,
                                        float& b0, float& b1, float& b2,
                                        int& i0, int& i1, int& i2) {
    if (d < b2) {
        if (d < b1) {
            b2 = b1; i2 = i1;
            if (d < b0) { b1 = b0; i1 = i0; b0 = d; i0 = j; }
            else        { b1 = d;  i1 = j; }
        } else { b2 = d; i2 = j; }
    }
}

// ---- Phase 0: fused prep — W1/W2 convert+transpose, pos4 build, out tail ---
__global__ __launch_bounds__(256) void prep_tail_kernel(
        const float* __restrict__ W1, const float* __restrict__ W2,
        const float* __restrict__ pos, const float* __restrict__ pos_skip,
        __hip_bfloat16* __restrict__ W1t, __hip_bfloat16* __restrict__ W2t,
        float4* __restrict__ pos4, float* __restrict__ out, int out_size) {
    const int i = blockIdx.x * 256 + threadIdx.x;
    if (i < C_H * HDIM) {
        const int k = i / HDIM, n = i % HDIM;
        W1t[n * C_H + k] = __float2bfloat16(W1[i]);
    } else if (i < C_H * HDIM + HDIM * HDIM) {
        const int j = i - C_H * HDIM;
        const int k = j / HDIM, n = j % HDIM;
        W2t[n * HDIM + k] = __float2bfloat16(W2[j]);
    } else if (i < C_H * HDIM + HDIM * HDIM + N_PTS) {
        const int j = i - (C_H * HDIM + HDIM * HDIM);
        const float px = pos[j*3+0], py = pos[j*3+1], pz = pos[j*3+2];
        pos4[j] = make_float4(px, py, pz, px*px + py*py + pz*pz);
    }
    // output tail: pos_skip passthrough + zero pad (runs before mega writes)
    if (i < M_Q * 3) out[(size_t)M_Q * HDIM + i] = pos_skip[i];
    const int zbase = M_Q * HDIM + M_Q * 3;
    if (zbase + i < out_size) out[zbase + i] = 0.0f;
}

// ---- Mega kernel v3: kNN + merge + gather + MLP, LDS-reuse, 1 block/CU ----
// 64 queries/block, 512 thr = 8 waves. Phase A: posL staged (64 KB), wave w
// scans 512 points via uniform ds_read broadcast, lane = query. Phase B:
// wave-0 merge (24 cands/query), weights from surrogate d' + |q|^2.
// Phase C: h[64][392] OVERLAYS dead posL; candD/I overlay not-yet-live hid.
// GEMM1 -> ReLU -> hid -> GEMM2 -> out with register-double-buffered weight
// fragments direct from L2 (barrier-free K-loops). LDS 100.8 KB, grid 256.
__global__ __launch_bounds__(512) void mega_kernel(
        const float4* __restrict__ pos4, const float* __restrict__ pos_skip,
        const float* __restrict__ x, const float* __restrict__ x_skip,
        const __bf16* __restrict__ W1t, const __bf16* __restrict__ W2t,
        const float* __restrict__ b1, const float* __restrict__ b2,
        float* __restrict__ out) {
    __shared__ __align__(16) char smem[100864];
    float4*         posL  = (float4*)smem;                    // [4096]  64 KB  (phase A)
    __hip_bfloat16* h     = (__hip_bfloat16*)smem;            // [64][392] 50.2 KB (phase C, overlays posL)
    __hip_bfloat16* hid   = (__hip_bfloat16*)(smem + 65536);  // [64][264] 33.8 KB (phase D)
    float*          candD = (float*)(smem + 65536);           // [8][64][3] (phase A/B, overlays hid)
    int*            candI = (int*)  (smem + 71680);           // [8][64][3]
    int*            idxL  = (int*)  (smem + 99328);           // [192]
    float*          wnL   = (float*)(smem + 100096);          // [192]

    const int t    = threadIdx.x;
    const int m0   = blockIdx.x * QB;
    const int wave = t >> 6, lane = t & 63;

    // ---- stage all points (coalesced, 8 float4/thread) ----
    #pragma unroll
    for (int k = 0; k < N_PTS / 512; ++k)
        posL[k * 512 + t] = pos4[k * 512 + t];

    // ---- preload x_skip to regs: consumed after merge (T14 issue-early) ----
    float4 skipv[4];
    #pragma unroll
    for (int p = 0; p < 4; ++p) {
        const int g = p * 512 + t;                 // 0..2047
        const int r = g >> 5, c = (g & 31) * 4;
        skipv[p] = *(const float4*)(x_skip + (size_t)(m0 + r) * C_SKIP + c);
    }

    const int q = m0 + lane;
    const float qx = pos_skip[q*3+0], qy = pos_skip[q*3+1], qz = pos_skip[q*3+2];
    const float m2x = -2.0f * qx, m2y = -2.0f * qy, m2z = -2.0f * qz;
    __syncthreads();

    // ---- Phase A: kNN scan; wave w owns points [w*512,(w+1)*512) ----
    {
        const int j0 = wave * (N_PTS / 8);
        float bb0 = 3e38f, bb1 = 3e38f, bb2 = 3e38f;
        int   ii0 = 0, ii1 = 0, ii2 = 0;
        #pragma unroll 8
        for (int j = 0; j < N_PTS / 8; ++j) {
            const float4 p = posL[j0 + j];         // uniform addr -> LDS broadcast
            const float d = fmaf(p.x, m2x, fmaf(p.y, m2y, fmaf(p.z, m2z, p.w)));
            const int  jj = j0 + j;
            const bool c0 = d < bb0, c1 = d < bb1, c2 = d < bb2;
            ii2 = c2 ? (c1 ? ii1 : jj) : ii2;
            ii1 = c1 ? (c0 ? ii0 : jj) : ii1;
            ii0 = c0 ? jj : ii0;
            bb2 = __builtin_amdgcn_fmed3f(d, bb1, bb2);  // branch-free top-3 values
            bb1 = __builtin_amdgcn_fmed3f(d, bb0, bb1);
            bb0 = fminf(bb0, d);
        }
        const int ci = (wave * 64 + lane) * 3;
        candD[ci+0] = bb0; candD[ci+1] = bb1; candD[ci+2] = bb2;
        candI[ci+0] = ii0; candI[ci+1] = ii1; candI[ci+2] = ii2;
    }
    __syncthreads();

    // ---- Phase B: merge 24 cands/query (wave 0, lane = query) ----
    if (t < 64) {
        float B0 = 3e38f, B1 = 3e38f, B2v = 3e38f;
        int   I0 = 0, I1 = 0, I2 = 0;
        #pragma unroll
        for (int ww = 0; ww < 8; ++ww) {           // ascending wave = ascending j
            const int ci = (ww * 64 + t) * 3;
            insert3(candD[ci+0], candI[ci+0], B0,B1,B2v, I0,I1,I2);
            insert3(candD[ci+1], candI[ci+1], B0,B1,B2v, I0,I1,I2);
            insert3(candD[ci+2], candI[ci+2], B0,B1,B2v, I0,I1,I2);
        }
        // exact d2 = surrogate d' + |q|^2 (verified rounds 2-4)
        const float qq = qx*qx + qy*qy + qz*qz;
        const float w0 = 1.0f / fmaxf(B0  + qq, 1e-16f);
        const float w1 = 1.0f / fmaxf(B1  + qq, 1e-16f);
        const float w2 = 1.0f / fmaxf(B2v + qq, 1e-16f);
        const float inv = 1.0f / (w0 + w1 + w2);
        idxL[t*3+0] = I0; idxL[t*3+1] = I1; idxL[t*3+2] = I2;
        wnL[t*3+0] = w0*inv; wnL[t*3+1] = w1*inv; wnL[t*3+2] = w2*inv;
    }
    __syncthreads();   // posL dead from here; candD/I dead after this barrier

    const int ln = lane & 15, kq = lane >> 4;
    const int wm  = (wave >> 2) * 32;   // 2 m-wave-rows of 32
    const int wnc = (wave & 3) * 64;    // 4 n-wave-cols of 64

    // ---- weight frag prefetch (k=0,32): in flight during gather ----
    bf16x8 bfA[4], bfB[4];
    #pragma unroll
    for (int nt = 0; nt < 4; ++nt) {
        bfA[nt] = *(const bf16x8*)(W1t + (size_t)(wnc + nt*16 + ln) * C_H +  0 + kq*8);
        bfB[nt] = *(const bf16x8*)(W1t + (size_t)(wnc + nt*16 + ln) * C_H + 32 + kq*8);
    }

    // ---- Phase C: skip concat (from regs) + gather-interp into h ----
    #pragma unroll
    for (int p = 0; p < 4; ++p) {
        const int g = p * 512 + t;
        const int r = g >> 5, c = (g & 31) * 4;
        union { __hip_bfloat162 v2[2]; uint2 u; } pk;
        pk.v2[0].x = __float2bfloat16(skipv[p].x); pk.v2[0].y = __float2bfloat16(skipv[p].y);
        pk.v2[1].x = __float2bfloat16(skipv[p].z); pk.v2[1].y = __float2bfloat16(skipv[p].w);
        *(uint2*)&h[(size_t)r * 392 + C_IN + c] = pk.u;
    }
    #pragma unroll 4
    for (int p = 0; p < 8; ++p) {
        const int g = p * 512 + t;                 // 0..4095
        const int r = g >> 6, c = (g & 63) * 4;
        const int   i0 = idxL[r*3+0], i1 = idxL[r*3+1], i2 = idxL[r*3+2];
        const float w0 = wnL[r*3+0],  w1 = wnL[r*3+1],  w2 = wnL[r*3+2];
        const float4 v0 = *(const float4*)(x + (size_t)i0 * C_IN + c);
        const float4 v1 = *(const float4*)(x + (size_t)i1 * C_IN + c);
        const float4 v2 = *(const float4*)(x + (size_t)i2 * C_IN + c);
        union { __hip_bfloat162 v2_[2]; uint2 u; } pk;
        pk.v2_[0].x = __float2bfloat16(w0*v0.x + w1*v1.x + w2*v2.x);
        pk.v2_[0].y = __float2bfloat16(w0*v0.y + w1*v1.y + w2*v2.y);
        pk.v2_[1].x = __float2bfloat16(w0*v0.z + w1*v1.z + w2*v2.z);
        pk.v2_[1].y = __float2bfloat16(w0*v0.w + w1*v1.w + w2*v2.w);
        *(uint2*)&h[(size_t)r * 392 + c] = pk.u;
    }
    __syncthreads();   // h complete

    f32x4 acc[2][4] = {};

    // ---- stage 1: hid = relu(h @ W1t^T + b1), K=384, barrier-free ----
    // reg-double-buffered W1 frags; full unroll -> compile-time buffer parity
    #pragma unroll
    for (int s = 0; s < 12; ++s) {
        const int k0 = s * 32;
        bf16x8* bc = (s & 1) ? bfB : bfA;
        const bf16x8 a0 = *(const bf16x8*)&h[(size_t)(wm +      ln) * 392 + k0 + kq*8];
        const bf16x8 a1 = *(const bf16x8*)&h[(size_t)(wm + 16 + ln) * 392 + k0 + kq*8];
        #pragma unroll
        for (int nt = 0; nt < 4; ++nt)
            acc[0][nt] = __builtin_amdgcn_mfma_f32_16x16x32_bf16(a0, bc[nt], acc[0][nt], 0,0,0);
        #pragma unroll
        for (int nt = 0; nt < 4; ++nt)
            acc[1][nt] = __builtin_amdgcn_mfma_f32_16x16x32_bf16(a1, bc[nt], acc[1][nt], 0,0,0);
        if (s < 10) {                              // refill for step s+2 (W1)
            #pragma unroll
            for (int nt = 0; nt < 4; ++nt)
                bc[nt] = *(const bf16x8*)(W1t + (size_t)(wnc + nt*16 + ln) * C_H + (k0 + 64) + kq*8);
        } else {                                   // first W2 tiles (stage-2 steps 0,1)
            #pragma unroll
            for (int nt = 0; nt < 4; ++nt)
                bc[nt] = *(const bf16x8*)(W2t + (size_t)(wnc + nt*16 + ln) * HDIM + (s - 10) * 32 + kq*8);
        }
    }

    // stage-1 epilogue: bias + relu -> hid (LDS), reset acc
    #pragma unroll
    for (int nt = 0; nt < 4; ++nt) {
        const int n = wnc + nt*16 + ln;
        const float bv = b1[n];
        #pragma unroll
        for (int mt = 0; mt < 2; ++mt) {
            const int rbase = wm + mt*16 + kq*4;
            #pragma unroll
            for (int r = 0; r < 4; ++r) {
                const float v = fmaxf(acc[mt][nt][r] + bv, 0.0f);
                hid[(size_t)(rbase + r) * 264 + n] = __float2bfloat16(v);
                acc[mt][nt][r] = 0.0f;
            }
        }
    }
    __syncthreads();

    // ---- stage 2: out = hid @ W2t^T + b2, K=256, barrier-free ----
    #pragma unroll
    for (int s = 0; s < 8; ++s) {
        const int k0 = s * 32;
        bf16x8* bc = (s & 1) ? bfB : bfA;          // parity continues from stage 1
        const bf16x8 a0 = *(const bf16x8*)&hid[(size_t)(wm +      ln) * 264 + k0 + kq*8];
        const bf16x8 a1 = *(const bf16x8*)&hid[(size_t)(wm + 16 + ln) * 264 + k0 + kq*8];
        #pragma unroll
        for (int nt = 0; nt < 4; ++nt)
            acc[0][nt] = __builtin_amdgcn_mfma_f32_16x16x32_bf16(a0, bc[nt], acc[0][nt], 0,0,0);
        #pragma unroll
        for (int nt = 0; nt < 4; ++nt)
            acc[1][nt] = __builtin_amdgcn_mfma_f32_16x16x32_bf16(a1, bc[nt], acc[1][nt], 0,0,0);
        if (s < 6) {
            #pragma unroll
            for (int nt = 0; nt < 4; ++nt)
                bc[nt] = *(const bf16x8*)(W2t + (size_t)(wnc + nt*16 + ln) * HDIM + (k0 + 64) + kq*8);
        }
    }

    // stage-2 epilogue: bias -> out (fp32)
    #pragma unroll
    for (int nt = 0; nt < 4; ++nt) {
        const int n = wnc + nt*16 + ln;
        const float bv = b2[n];
        #pragma unroll
        for (int mt = 0; mt < 2; ++mt) {
            const int rbase = m0 + wm + mt*16 + kq*4;
            #pragma unroll
            for (int r = 0; r < 4; ++r)
                out[(size_t)(rbase + r) * HDIM + n] = acc[mt][nt][r] + bv;
        }
    }
}

extern "C" void kernel_launch(void* const* d_in, const int* in_sizes, int n_in,
                              void* d_out, int out_size, void* d_ws, size_t ws_size,
                              hipStream_t stream) {
    (void)in_sizes; (void)n_in; (void)ws_size;
    const float* x        = (const float*)d_in[0];   // [4096,256]
    const float* pos      = (const float*)d_in[1];   // [4096,3]
    const float* x_skip   = (const float*)d_in[3];   // [16384,128]
    const float* pos_skip = (const float*)d_in[4];   // [16384,3]
    const float* W1       = (const float*)d_in[6];   // [384,256]
    const float* b1       = (const float*)d_in[7];   // [256]
    const float* W2       = (const float*)d_in[8];   // [256,256]
    const float* b2       = (const float*)d_in[9];   // [256]
    float* out = (float*)d_out;

    char* ws = (char*)d_ws;
    __hip_bfloat16* W1t  = (__hip_bfloat16*)(ws);           // 196,608
    __hip_bfloat16* W2t  = (__hip_bfloat16*)(ws + 196608);  // 131,072
    float4*         pos4 = (float4*)(ws + 327680);          //  65,536
                                                            // total 384 KB

    prep_tail_kernel<<<(C_H*HDIM + HDIM*HDIM + N_PTS + 255)/256, 256, 0, stream>>>(
        W1, W2, pos, pos_skip, W1t, W2t, pos4, out, out_size);
    mega_kernel<<<M_Q/QB, 512, 0, stream>>>(
        pos4, pos_skip, x, x_skip, (const __bf16*)W1t, (const __bf16*)W2t, b1, b2, out);
}